// Round 6
// baseline (4020.586 us; speedup 1.0000x reference)
//
#include <hip/hip_runtime.h>
#include <hip/hip_bf16.h>
#include <math.h>

// Problem constants
#define NN   4
#define MM   2048
#define CC   512
#define HH   8
#define DD   64
#define TK   16
#define QKVC 1536      // 3*CC

// f32(512**-0.5): NEP50 casts the python-float scale to f32 before the ufunc mul
#define SCALE32 ((float)0.044194173824159216)

// strict f32 multiply that cannot be contracted into a downstream FMA
__device__ __forceinline__ float fmul_nf(float a, float b) {
  float p = a * b;
  asm volatile("" : "+v"(p));
  return p;
}

// "a strictly precedes b" in top-k order (value desc, index asc on ties) — f32 values
__device__ __forceinline__ bool gtpf(float v1, int i1, float v2, int i2) {
  return (v1 > v2) || (v1 == v2 && i1 < i2);
}

// ---------------- Kernel 1 (per-n): conv + QKV GEMM, f32 np-mimicry ------------------
// x2 = x + (((x[-1]*w0 + x[0]*w1) + x[1]*w2) + cb)   [ufunc order, no FMA]
// q/k/v = x2 @ w_qkv (+0): f32, sequential k=0..511, FMA per step (BLAS-style).
__global__ __launch_bounds__(256) void gemm_conv_qkv_kernel(
    const float* __restrict__ x,
    const float* __restrict__ cw,
    const float* __restrict__ cb,
    const float* __restrict__ wqkv,
    const float* __restrict__ bqkv,
    float* __restrict__ Q, float* __restrict__ K, float* __restrict__ V)
{
  __shared__ float As[16][68];    // [k][row], x2 tile
  __shared__ float Bs[16][68];    // [k][col], weights
  __shared__ float cwb[CC*4];     // [c*4+{0,1,2}]=taps, [c*4+3]=bias

  int tid = threadIdx.x;
  for (int i = tid; i < CC; i += 256) {
    cwb[i*4+0] = cw[i*3+0];
    cwb[i*4+1] = cw[i*3+1];
    cwb[i*4+2] = cw[i*3+2];
    cwb[i*4+3] = cb[i];
  }

  int bm = blockIdx.x, bn = blockIdx.y;
  int tx = tid & 15, ty = tid >> 4;
  int ar = tid >> 2;               // tile row 0..63
  int ak = (tid & 3) << 2;         // k offset 0,4,8,12
  int brow = tid >> 4;             // 0..15
  int bcol = (tid & 15) << 2;      // 0..60
  int m = bm*64 + ar;              // row within this n
  const float* xp = x + (size_t)m*CC;
  const float* wp = wqkv + (size_t)brow*QKVC + bn*64 + bcol;

  float acc[4][4];
  #pragma unroll
  for (int i=0;i<4;i++)
    #pragma unroll
    for (int j=0;j<4;j++) acc[i][j]=0.f;

  for (int kt = 0; kt < CC/16; ++kt) {
    int c0 = kt*16 + ak;
    float4 x0  = *(const float4*)(xp + c0);
    float4 xm1 = make_float4(0.f,0.f,0.f,0.f);
    float4 xp1 = make_float4(0.f,0.f,0.f,0.f);
    if (m > 0)      xm1 = *(const float4*)(xp - CC + c0);
    if (m < MM - 1) xp1 = *(const float4*)(xp + CC + c0);
    float4 wv = *(const float4*)(wp + (size_t)kt*16*QKVC);

    __syncthreads();
    {
      const float xe[4]  = {x0.x,  x0.y,  x0.z,  x0.w};
      const float xme[4] = {xm1.x, xm1.y, xm1.z, xm1.w};
      const float xpe[4] = {xp1.x, xp1.y, xp1.z, xp1.w};
      #pragma unroll
      for (int e = 0; e < 4; ++e) {
        int c = c0 + e;
        // ufunc order, each op individually rounded, no FMA:
        float p0 = fmul_nf(xme[e], cwb[c*4+0]);   // pad-zero lanes give exact 0
        float p1 = fmul_nf(xe[e],  cwb[c*4+1]);
        float p2 = fmul_nf(xpe[e], cwb[c*4+2]);
        float s  = p0 + p1;
        s = s + p2;
        s = s + cwb[c*4+3];
        As[ak+e][ar] = xe[e] + s;                 // x2 = x + pos
      }
    }
    *(float4*)&Bs[brow][bcol] = wv;
    __syncthreads();

    // sequential-k FMA accumulation (per output element: k ascending overall)
    #pragma unroll
    for (int kk = 0; kk < 16; ++kk) {
      float4 a4 = *(const float4*)&As[kk][ty<<2];
      float4 b4 = *(const float4*)&Bs[kk][tx<<2];
      const float ae[4] = {a4.x, a4.y, a4.z, a4.w};
      const float be[4] = {b4.x, b4.y, b4.z, b4.w};
      #pragma unroll
      for (int i=0;i<4;i++)
        #pragma unroll
        for (int j=0;j<4;j++)
          acc[i][j] = __builtin_fmaf(ae[i], be[j], acc[i][j]);
    }
  }

  int orow = bm*64 + (ty<<2);
  int seg  = bn >> 3;                       // 0=q, 1=k, 2=v
  float* dst = (seg==0) ? Q : ((seg==1) ? K : V);
  int col  = (bn & 7)*64 + (tx<<2);
  float bb[4];
  #pragma unroll
  for (int j=0;j<4;j++) bb[j] = bqkv[bn*64 + (tx<<2) + j];
  #pragma unroll
  for (int i=0;i<4;i++) {
    float4 o = make_float4(acc[i][0]+bb[0], acc[i][1]+bb[1],
                           acc[i][2]+bb[2], acc[i][3]+bb[3]);
    *(float4*)&dst[(size_t)(orow+i)*CC + col] = o;
  }
}

// ---------------- Kernel 2 (per-n): f32 logits + top-16 + softmax + V-gather --------
// logits: (q*scale32 rounded to f32) · k, sequential d=0..63, separate mul+add
// (einsum sum-of-products, no FMA). Top-16 on (f32 value, idx) with stable ties.
__global__ __launch_bounds__(256) void route_attn_kernel(
    const float* __restrict__ Q,
    const float* __restrict__ K,
    const float* __restrict__ V,
    float* __restrict__ attn)
{
  __shared__ float qs[16][68];    // q*scale32, f32-rounded (np's qd*scale array)
  __shared__ float ks[64][68];
  int bq = blockIdx.x;
  int h = bq >> 7, qt = bq & 127;
  int tid = threadIdx.x;
  int s = tid & 15, qi = tid >> 4;

  { // stage q tile, apply scale in f32 (single rounding, matches np ufunc)
    int r = tid >> 4, c4 = tid & 15;
    const float* p = Q + (size_t)(qt*16 + r)*CC + h*DD + (c4<<2);
    float4 v = *(const float4*)p;
    qs[r][(c4<<2)+0] = v.x * SCALE32;
    qs[r][(c4<<2)+1] = v.y * SCALE32;
    qs[r][(c4<<2)+2] = v.z * SCALE32;
    qs[r][(c4<<2)+3] = v.w * SCALE32;
  }

  float lv[16]; int li[16];
  #pragma unroll
  for (int i=0;i<16;i++){ lv[i] = -INFINITY; li[i] = i; }

  for (int kt = 0; kt < 32; ++kt) {      // 32 tiles x 64 keys
    __syncthreads();
    #pragma unroll
    for (int rep = 0; rep < 4; ++rep) {
      int idx = tid + (rep<<8);          // 0..1023
      int r = idx >> 4, c4 = idx & 15;
      *(float4*)&ks[r][c4<<2] =
          *(const float4*)(K + (size_t)(kt*64 + r)*CC + h*DD + (c4<<2));
    }
    __syncthreads();

    float acc[4];
    #pragma unroll
    for (int j=0;j<4;j++) acc[j]=0.f;
    for (int t = 0; t < 64; ++t) {       // sequential d, mul then add, no FMA
      float qv = qs[qi][t];
      #pragma unroll
      for (int j=0;j<4;j++) {
        float p = fmul_nf(qv, ks[s + (j<<4)][t]);
        acc[j] = acc[j] + p;
      }
    }
    // streaming insert; within-thread key idx strictly increases, so on exact tie
    // the incumbent (smaller idx) correctly wins via strict >
    #pragma unroll
    for (int j=0;j<4;j++) {
      float v = acc[j];
      if (v > lv[15]) {
        lv[15] = v; li[15] = kt*64 + s + (j<<4);
        #pragma unroll
        for (int p = 15; p >= 1; --p) {
          if (gtpf(lv[p], li[p], lv[p-1], li[p-1])) {
            float tv = lv[p]; lv[p] = lv[p-1]; lv[p-1] = tv;
            int   ti = li[p]; li[p] = li[p-1]; li[p-1] = ti;
          }
        }
      }
    }
  }

  // 16-lane butterfly merge; all lanes converge to the identical global top-16
  #pragma unroll
  for (int off = 1; off < 16; off <<= 1) {
    float nv[16]; int ni[16];
    #pragma unroll
    for (int i = 0; i < 16; ++i) {       // half-cleaner
      float bv = __shfl_xor(lv[15 - i], off);
      int   bi = __shfl_xor(li[15 - i], off);
      bool g = gtpf(lv[i], li[i], bv, bi);
      nv[i] = g ? lv[i] : bv;
      ni[i] = g ? li[i] : bi;
    }
    #pragma unroll
    for (int d = 8; d >= 1; d >>= 1) {   // bitonic -> sorted desc
      #pragma unroll
      for (int i = 0; i < 16; ++i) {
        if ((i & d) == 0) {
          if (!gtpf(nv[i], ni[i], nv[i+d], ni[i+d])) {
            float tv = nv[i]; nv[i] = nv[i+d]; nv[i+d] = tv;
            int   ti = ni[i]; ni[i] = ni[i+d]; ni[i+d] = ti;
          }
        }
      }
    }
    #pragma unroll
    for (int i = 0; i < 16; ++i) { lv[i] = nv[i]; li[i] = ni[i]; }
  }

  // softmax (f32) + V gather: lane s handles dims [4s, 4s+4)
  float e[16]; float Z = 0.f;
  float mx = lv[0];                 // sorted desc -> max
  #pragma unroll
  for (int i=0;i<16;i++){ e[i] = expf(lv[i]-mx); Z += e[i]; }
  float invZ = 1.f / Z;
  float4 o = make_float4(0.f,0.f,0.f,0.f);
  #pragma unroll
  for (int i=0;i<16;i++) {
    int ki = li[i] & (MM - 1);          // masked: can never read wild
    const float* vp = V + (size_t)ki*CC + h*DD + (s<<2);
    float4 vv = *(const float4*)vp;
    float w = e[i]*invZ;
    o.x += w*vv.x; o.y += w*vv.y; o.z += w*vv.z; o.w += w*vv.w;
  }
  *(float4*)&attn[(size_t)(qt*16 + qi)*CC + h*DD + (s<<2)] = o;
}

// ---------------- Kernel 3 (per-n): f32 GEMM out = attn @ w_o + b_o -> f32 ----------
__global__ __launch_bounds__(256) void gemm_out_kernel(
    const float* __restrict__ A,
    const float* __restrict__ W,
    const float* __restrict__ bias,
    float* __restrict__ O,
    int ncols)
{
  __shared__ float As[16][68];
  __shared__ float Bs[16][68];
  int tid = threadIdx.x;
  int bm = blockIdx.x, bn = blockIdx.y;
  int tx = tid & 15, ty = tid >> 4;
  int ar = tid >> 2;
  int ak = (tid & 3) << 2;
  int brow = tid >> 4;
  int bcol = (tid & 15) << 2;
  const float* Ap = A + (size_t)(bm*64 + ar)*CC + ak;
  const float* Wp = W + (size_t)brow*ncols + bn*64 + bcol;

  float acc[4][4];
  #pragma unroll
  for (int i=0;i<4;i++)
    #pragma unroll
    for (int j=0;j<4;j++) acc[i][j]=0.f;

  for (int kt = 0; kt < CC/16; ++kt) {
    float4 av = *(const float4*)(Ap + kt*16);
    float4 wv = *(const float4*)(Wp + (size_t)kt*16*ncols);
    __syncthreads();
    As[ak+0][ar]=av.x; As[ak+1][ar]=av.y; As[ak+2][ar]=av.z; As[ak+3][ar]=av.w;
    *(float4*)&Bs[brow][bcol] = wv;
    __syncthreads();
    #pragma unroll
    for (int kk = 0; kk < 16; ++kk) {
      float4 a4 = *(const float4*)&As[kk][ty<<2];
      float4 b4 = *(const float4*)&Bs[kk][tx<<2];
      const float ae[4] = {a4.x, a4.y, a4.z, a4.w};
      const float be[4] = {b4.x, b4.y, b4.z, b4.w};
      #pragma unroll
      for (int i=0;i<4;i++)
        #pragma unroll
        for (int j=0;j<4;j++)
          acc[i][j] = __builtin_fmaf(ae[i], be[j], acc[i][j]);
    }
  }
  int row = bm*64 + (ty<<2);
  int col = bn*64 + (tx<<2);
  float bb[4];
  #pragma unroll
  for (int j=0;j<4;j++) bb[j] = bias[col+j];
  #pragma unroll
  for (int i=0;i<4;i++) {
    float4 o = make_float4(acc[i][0]+bb[0], acc[i][1]+bb[1],
                           acc[i][2]+bb[2], acc[i][3]+bb[3]);
    *(float4*)&O[(size_t)(row+i)*ncols + col] = o;
  }
}

// ---------------- launch --------------------------------------------------------------
extern "C" void kernel_launch(void* const* d_in, const int* in_sizes, int n_in,
                              void* d_out, int out_size, void* d_ws, size_t ws_size,
                              hipStream_t stream) {
  (void)in_sizes; (void)n_in; (void)out_size; (void)ws_size;
  const float* x      = (const float*)d_in[0];
  const float* conv_w = (const float*)d_in[1];
  const float* conv_b = (const float*)d_in[2];
  const float* w_qkv  = (const float*)d_in[3];
  const float* b_qkv  = (const float*)d_in[4];
  const float* w_o    = (const float*)d_in[5];
  const float* b_o    = (const float*)d_in[6];
  float* out = (float*)d_out;

  // Per-n workspace: Q,K,V,attn f32 [MM][CC] = 4 x 4MB = 16 MB total
  float* Qb = (float*)d_ws;
  float* Kb = Qb + (size_t)MM*CC;
  float* Vb = Kb + (size_t)MM*CC;
  float* at = Vb + (size_t)MM*CC;

  for (int n = 0; n < NN; ++n) {
    const float* xn = x + (size_t)n*MM*CC;
    gemm_conv_qkv_kernel<<<dim3(MM/64, QKVC/64), 256, 0, stream>>>(
        xn, conv_w, conv_b, w_qkv, b_qkv, Qb, Kb, Vb);
    route_attn_kernel<<<HH*(MM/16), 256, 0, stream>>>(Qb, Kb, Vb, at);
    gemm_out_kernel<<<dim3(MM/64, CC/64), 256, 0, stream>>>(
        at, w_o, b_o, out + (size_t)n*MM*CC, CC);
  }
}

// Round 7
// 1477.360 us; speedup vs baseline: 2.7215x; 2.7215x over previous
//
#include <hip/hip_runtime.h>
#include <hip/hip_bf16.h>
#include <math.h>

// Problem constants
#define NN   4
#define MM   2048
#define CC   512
#define HH   8
#define DD   64
#define TK   16
#define QKVC 1536      // 3*CC

// f32(512**-0.5): NEP50 casts the python-float scale to f32 before the ufunc mul
#define SCALE32 ((float)0.044194173824159216)

// strict f32 multiply that cannot be contracted into a downstream FMA
__device__ __forceinline__ float fmul_nf(float a, float b) {
  float p = a * b;
  asm volatile("" : "+v"(p));
  return p;
}

// "a strictly precedes b" in top-k order (value desc, index asc on ties) — f32 values
__device__ __forceinline__ bool gtpf(float v1, int i1, float v2, int i2) {
  return (v1 > v2) || (v1 == v2 && i1 < i2);
}

// ---------------- Kernel 1 (per-n): conv + QKV GEMM, f32 np-mimicry ------------------
// x2 = x + (((x[-1]*w0 + x[0]*w1) + x[1]*w2) + cb)   [ufunc order, no FMA]
// q/k/v = x2 @ w_qkv (+bias): f32, sequential k=0..511, FMA per step.  UNCHANGED.
__global__ __launch_bounds__(256) void gemm_conv_qkv_kernel(
    const float* __restrict__ x,
    const float* __restrict__ cw,
    const float* __restrict__ cb,
    const float* __restrict__ wqkv,
    const float* __restrict__ bqkv,
    float* __restrict__ Q, float* __restrict__ K, float* __restrict__ V)
{
  __shared__ float As[16][68];    // [k][row], x2 tile
  __shared__ float Bs[16][68];    // [k][col], weights
  __shared__ float cwb[CC*4];     // [c*4+{0,1,2}]=taps, [c*4+3]=bias

  int tid = threadIdx.x;
  for (int i = tid; i < CC; i += 256) {
    cwb[i*4+0] = cw[i*3+0];
    cwb[i*4+1] = cw[i*3+1];
    cwb[i*4+2] = cw[i*3+2];
    cwb[i*4+3] = cb[i];
  }

  int bm = blockIdx.x, bn = blockIdx.y;
  int tx = tid & 15, ty = tid >> 4;
  int ar = tid >> 2;               // tile row 0..63
  int ak = (tid & 3) << 2;         // k offset 0,4,8,12
  int brow = tid >> 4;             // 0..15
  int bcol = (tid & 15) << 2;      // 0..60
  int m = bm*64 + ar;              // row within this n
  const float* xp = x + (size_t)m*CC;
  const float* wp = wqkv + (size_t)brow*QKVC + bn*64 + bcol;

  float acc[4][4];
  #pragma unroll
  for (int i=0;i<4;i++)
    #pragma unroll
    for (int j=0;j<4;j++) acc[i][j]=0.f;

  for (int kt = 0; kt < CC/16; ++kt) {
    int c0 = kt*16 + ak;
    float4 x0  = *(const float4*)(xp + c0);
    float4 xm1 = make_float4(0.f,0.f,0.f,0.f);
    float4 xp1 = make_float4(0.f,0.f,0.f,0.f);
    if (m > 0)      xm1 = *(const float4*)(xp - CC + c0);
    if (m < MM - 1) xp1 = *(const float4*)(xp + CC + c0);
    float4 wv = *(const float4*)(wp + (size_t)kt*16*QKVC);

    __syncthreads();
    {
      const float xe[4]  = {x0.x,  x0.y,  x0.z,  x0.w};
      const float xme[4] = {xm1.x, xm1.y, xm1.z, xm1.w};
      const float xpe[4] = {xp1.x, xp1.y, xp1.z, xp1.w};
      #pragma unroll
      for (int e = 0; e < 4; ++e) {
        int c = c0 + e;
        float p0 = fmul_nf(xme[e], cwb[c*4+0]);
        float p1 = fmul_nf(xe[e],  cwb[c*4+1]);
        float p2 = fmul_nf(xpe[e], cwb[c*4+2]);
        float s  = p0 + p1;
        s = s + p2;
        s = s + cwb[c*4+3];
        As[ak+e][ar] = xe[e] + s;                 // x2 = x + pos
      }
    }
    *(float4*)&Bs[brow][bcol] = wv;
    __syncthreads();

    #pragma unroll
    for (int kk = 0; kk < 16; ++kk) {
      float4 a4 = *(const float4*)&As[kk][ty<<2];
      float4 b4 = *(const float4*)&Bs[kk][tx<<2];
      const float ae[4] = {a4.x, a4.y, a4.z, a4.w};
      const float be[4] = {b4.x, b4.y, b4.z, b4.w};
      #pragma unroll
      for (int i=0;i<4;i++)
        #pragma unroll
        for (int j=0;j<4;j++)
          acc[i][j] = __builtin_fmaf(ae[i], be[j], acc[i][j]);
    }
  }

  int orow = bm*64 + (ty<<2);
  int seg  = bn >> 3;                       // 0=q, 1=k, 2=v
  float* dst = (seg==0) ? Q : ((seg==1) ? K : V);
  int col  = (bn & 7)*64 + (tx<<2);
  float bb[4];
  #pragma unroll
  for (int j=0;j<4;j++) bb[j] = bqkv[bn*64 + (tx<<2) + j];
  #pragma unroll
  for (int i=0;i<4;i++) {
    float4 o = make_float4(acc[i][0]+bb[0], acc[i][1]+bb[1],
                           acc[i][2]+bb[2], acc[i][3]+bb[3]);
    *(float4*)&dst[(size_t)(orow+i)*CC + col] = o;
  }
}

// ---------------- Kernel 2 (per-n): f32 logits + top-16 + softmax + V-gather --------
// v2: 32 queries/block, 128-key LDS tiles, float4 LDS reads, 2 queries/thread
// (k-fragment reuse). Per-logit FP op sequence is BIT-IDENTICAL to v1: t ascending,
// separate mul+add (fmul_nf barrier blocks contraction). Streaming insert per thread
// (key idx ascending), then 16-lane bitonic merge per query -> lax.top_k semantics.
__global__ __launch_bounds__(256) void route_attn_kernel(
    const float* __restrict__ Q,
    const float* __restrict__ K,
    const float* __restrict__ V,
    float* __restrict__ attn)
{
  __shared__ float qs[32][68];    // q*scale32 (f32-rounded), 32 queries
  __shared__ float ks[128][68];   // staged k-tile
  int bq = blockIdx.x;
  int h = bq >> 6, qt = bq & 63;  // 64 q-tiles of 32
  int tid = threadIdx.x;
  int s = tid & 15, qi = tid >> 4;   // qi 0..15; thread owns queries qi and qi+16

  // stage q tile (32 rows x 16 float4), scale applied once in f32
  #pragma unroll
  for (int rep = 0; rep < 2; ++rep) {
    int idx = tid + (rep<<8);
    int r = idx >> 4, c4 = idx & 15;
    const float* p = Q + (size_t)(qt*32 + r)*CC + h*DD + (c4<<2);
    float4 v = *(const float4*)p;
    qs[r][(c4<<2)+0] = v.x * SCALE32;
    qs[r][(c4<<2)+1] = v.y * SCALE32;
    qs[r][(c4<<2)+2] = v.z * SCALE32;
    qs[r][(c4<<2)+3] = v.w * SCALE32;
  }

  float lvA[16], lvB[16]; int liA[16], liB[16];
  #pragma unroll
  for (int i=0;i<16;i++){ lvA[i]=-INFINITY; liA[i]=i; lvB[i]=-INFINITY; liB[i]=i; }

  for (int kt = 0; kt < 16; ++kt) {      // 16 tiles x 128 keys
    __syncthreads();
    #pragma unroll
    for (int rep = 0; rep < 8; ++rep) {
      int idx = tid + (rep<<8);          // 0..2047
      int r = idx >> 4, c4 = idx & 15;
      *(float4*)&ks[r][c4<<2] =
          *(const float4*)(K + (size_t)(kt*128 + r)*CC + h*DD + (c4<<2));
    }
    __syncthreads();

    float accA[8], accB[8];
    #pragma unroll
    for (int j=0;j<8;j++){ accA[j]=0.f; accB[j]=0.f; }

    for (int t4 = 0; t4 < 16; ++t4) {    // dims ascending: t = 4*t4 + {0,1,2,3}
      float4 qa = *(const float4*)&qs[qi][t4<<2];
      float4 qb = *(const float4*)&qs[qi+16][t4<<2];
      #pragma unroll
      for (int j = 0; j < 8; ++j) {
        float4 kv = *(const float4*)&ks[s + (j<<4)][t4<<2];
        // separate mul+add, sequential in t — same op chain as v1
        accA[j] = accA[j] + fmul_nf(qa.x, kv.x);
        accA[j] = accA[j] + fmul_nf(qa.y, kv.y);
        accA[j] = accA[j] + fmul_nf(qa.z, kv.z);
        accA[j] = accA[j] + fmul_nf(qa.w, kv.w);
        accB[j] = accB[j] + fmul_nf(qb.x, kv.x);
        accB[j] = accB[j] + fmul_nf(qb.y, kv.y);
        accB[j] = accB[j] + fmul_nf(qb.z, kv.z);
        accB[j] = accB[j] + fmul_nf(qb.w, kv.w);
      }
    }

    // streaming inserts; key idx = kt*128 + s + 16j ascending per thread, so on
    // exact value tie the incumbent (smaller idx) correctly wins via strict >
    #pragma unroll
    for (int j=0;j<8;j++) {
      int kidx = kt*128 + s + (j<<4);
      float v = accA[j];
      if (v > lvA[15]) {
        lvA[15] = v; liA[15] = kidx;
        #pragma unroll
        for (int p = 15; p >= 1; --p) {
          if (gtpf(lvA[p], liA[p], lvA[p-1], liA[p-1])) {
            float tv = lvA[p]; lvA[p] = lvA[p-1]; lvA[p-1] = tv;
            int   ti = liA[p]; liA[p] = liA[p-1]; liA[p-1] = ti;
          }
        }
      }
      v = accB[j];
      if (v > lvB[15]) {
        lvB[15] = v; liB[15] = kidx;
        #pragma unroll
        for (int p = 15; p >= 1; --p) {
          if (gtpf(lvB[p], liB[p], lvB[p-1], liB[p-1])) {
            float tv = lvB[p]; lvB[p] = lvB[p-1]; lvB[p-1] = tv;
            int   ti = liB[p]; liB[p] = liB[p-1]; liB[p-1] = ti;
          }
        }
      }
    }
  }

  // 16-lane butterfly merge + epilogue, list A then list B
  #pragma unroll
  for (int which = 0; which < 2; ++which) {
    float lv[16]; int li[16];
    #pragma unroll
    for (int i=0;i<16;i++){ lv[i] = which ? lvB[i] : lvA[i];
                            li[i] = which ? liB[i] : liA[i]; }
    #pragma unroll
    for (int off = 1; off < 16; off <<= 1) {
      float nv[16]; int ni[16];
      #pragma unroll
      for (int i = 0; i < 16; ++i) {       // half-cleaner
        float bv = __shfl_xor(lv[15 - i], off);
        int   bi = __shfl_xor(li[15 - i], off);
        bool g = gtpf(lv[i], li[i], bv, bi);
        nv[i] = g ? lv[i] : bv;
        ni[i] = g ? li[i] : bi;
      }
      #pragma unroll
      for (int d = 8; d >= 1; d >>= 1) {   // bitonic -> sorted desc
        #pragma unroll
        for (int i = 0; i < 16; ++i) {
          if ((i & d) == 0) {
            if (!gtpf(nv[i], ni[i], nv[i+d], ni[i+d])) {
              float tv = nv[i]; nv[i] = nv[i+d]; nv[i+d] = tv;
              int   ti = ni[i]; ni[i] = ni[i+d]; ni[i+d] = ti;
            }
          }
        }
      }
      #pragma unroll
      for (int i = 0; i < 16; ++i) { lv[i] = nv[i]; li[i] = ni[i]; }
    }

    // softmax (f32) + V gather: lane s handles dims [4s, 4s+4)
    float e[16]; float Z = 0.f;
    float mx = lv[0];                 // sorted desc -> max
    #pragma unroll
    for (int i=0;i<16;i++){ e[i] = expf(lv[i]-mx); Z += e[i]; }
    float invZ = 1.f / Z;
    float4 o = make_float4(0.f,0.f,0.f,0.f);
    #pragma unroll
    for (int i=0;i<16;i++) {
      int ki = li[i] & (MM - 1);          // masked: can never read wild
      const float* vp = V + (size_t)ki*CC + h*DD + (s<<2);
      float4 vv = *(const float4*)vp;
      float w = e[i]*invZ;
      o.x += w*vv.x; o.y += w*vv.y; o.z += w*vv.z; o.w += w*vv.w;
    }
    int qrow = qt*32 + qi + (which ? 16 : 0);
    *(float4*)&attn[(size_t)qrow*CC + h*DD + (s<<2)] = o;
  }
}

// ---------------- Kernel 3 (per-n): f32 GEMM out = attn @ w_o + b_o -> f32 ----------
__global__ __launch_bounds__(256) void gemm_out_kernel(
    const float* __restrict__ A,
    const float* __restrict__ W,
    const float* __restrict__ bias,
    float* __restrict__ O,
    int ncols)
{
  __shared__ float As[16][68];
  __shared__ float Bs[16][68];
  int tid = threadIdx.x;
  int bm = blockIdx.x, bn = blockIdx.y;
  int tx = tid & 15, ty = tid >> 4;
  int ar = tid >> 2;
  int ak = (tid & 3) << 2;
  int brow = tid >> 4;
  int bcol = (tid & 15) << 2;
  const float* Ap = A + (size_t)(bm*64 + ar)*CC + ak;
  const float* Wp = W + (size_t)brow*ncols + bn*64 + bcol;

  float acc[4][4];
  #pragma unroll
  for (int i=0;i<4;i++)
    #pragma unroll
    for (int j=0;j<4;j++) acc[i][j]=0.f;

  for (int kt = 0; kt < CC/16; ++kt) {
    float4 av = *(const float4*)(Ap + kt*16);
    float4 wv = *(const float4*)(Wp + (size_t)kt*16*ncols);
    __syncthreads();
    As[ak+0][ar]=av.x; As[ak+1][ar]=av.y; As[ak+2][ar]=av.z; As[ak+3][ar]=av.w;
    *(float4*)&Bs[brow][bcol] = wv;
    __syncthreads();
    #pragma unroll
    for (int kk = 0; kk < 16; ++kk) {
      float4 a4 = *(const float4*)&As[kk][ty<<2];
      float4 b4 = *(const float4*)&Bs[kk][tx<<2];
      const float ae[4] = {a4.x, a4.y, a4.z, a4.w};
      const float be[4] = {b4.x, b4.y, b4.z, b4.w};
      #pragma unroll
      for (int i=0;i<4;i++)
        #pragma unroll
        for (int j=0;j<4;j++)
          acc[i][j] = __builtin_fmaf(ae[i], be[j], acc[i][j]);
    }
  }
  int row = bm*64 + (ty<<2);
  int col = bn*64 + (tx<<2);
  float bb[4];
  #pragma unroll
  for (int j=0;j<4;j++) bb[j] = bias[col+j];
  #pragma unroll
  for (int i=0;i<4;i++) {
    float4 o = make_float4(acc[i][0]+bb[0], acc[i][1]+bb[1],
                           acc[i][2]+bb[2], acc[i][3]+bb[3]);
    *(float4*)&O[(size_t)(row+i)*ncols + col] = o;
  }
}

// ---------------- launch --------------------------------------------------------------
extern "C" void kernel_launch(void* const* d_in, const int* in_sizes, int n_in,
                              void* d_out, int out_size, void* d_ws, size_t ws_size,
                              hipStream_t stream) {
  (void)in_sizes; (void)n_in; (void)out_size; (void)ws_size;
  const float* x      = (const float*)d_in[0];
  const float* conv_w = (const float*)d_in[1];
  const float* conv_b = (const float*)d_in[2];
  const float* w_qkv  = (const float*)d_in[3];
  const float* b_qkv  = (const float*)d_in[4];
  const float* w_o    = (const float*)d_in[5];
  const float* b_o    = (const float*)d_in[6];
  float* out = (float*)d_out;

  // Per-n workspace: Q,K,V,attn f32 [MM][CC] = 4 x 4MB = 16 MB total
  float* Qb = (float*)d_ws;
  float* Kb = Qb + (size_t)MM*CC;
  float* Vb = Kb + (size_t)MM*CC;
  float* at = Vb + (size_t)MM*CC;

  for (int n = 0; n < NN; ++n) {
    const float* xn = x + (size_t)n*MM*CC;
    gemm_conv_qkv_kernel<<<dim3(MM/64, QKVC/64), 256, 0, stream>>>(
        xn, conv_w, conv_b, w_qkv, b_qkv, Qb, Kb, Vb);
    route_attn_kernel<<<HH*(MM/32), 256, 0, stream>>>(Qb, Kb, Vb, at);
    gemm_out_kernel<<<dim3(MM/64, CC/64), 256, 0, stream>>>(
        at, w_o, b_o, out + (size_t)n*MM*CC, CC);
  }
}